// Round 1
// baseline (1370.173 us; speedup 1.0000x reference)
//
#include <hip/hip_runtime.h>
#include <math.h>

typedef unsigned short u16;
typedef __bf16 bf16x8 __attribute__((ext_vector_type(8)));
typedef float f32x4  __attribute__((ext_vector_type(4)));
typedef u16   u16x4  __attribute__((ext_vector_type(4)));

#define GPTR(p) ((__attribute__((address_space(1))) void*)(p))
#define LPTR(p) ((__attribute__((address_space(3))) void*)(p))

__device__ __forceinline__ float bf2f(u16 h) { return __uint_as_float(((unsigned)h) << 16); }
__device__ __forceinline__ u16 f2bf(float f) {
    unsigned u = __float_as_uint(f);
    return (u16)((u + 0x7fffu + ((u >> 16) & 1u)) >> 16);
}
__device__ __forceinline__ float gelu_f(float x) {
    return 0.5f * x * (1.0f + erff(x * 0.7071067811865476f));
}

// ---------------------------------------------------------------------------
// GEMM: C = epilogue(A(MxK) @ B(NxK)^T), bf16 inputs, fp32 MFMA accumulate.
// 128x128 tile, 4 waves (each 64x64 = 4x4 of 16x16x32 mfma), BK=32,
// global_load_lds width-16 staging (m97 structure).
// MODE: 0=none, 1=scale, 2=+bias, 3=+bias,gelu, 4=+bias,gelu,+addend, 5=+bias fp32-out
// ---------------------------------------------------------------------------
template<int MODE>
__global__ __launch_bounds__(256)
void gemm_bt(const u16* __restrict__ A, int lda, long sA,
             const u16* __restrict__ B, int ldb, long sB,
             void* __restrict__ Cout, int ldc, long sC,
             const float* __restrict__ bias,
             const u16* __restrict__ addend,
             int K, float scale)
{
    __shared__ u16 lA[128 * 32];
    __shared__ u16 lB[128 * 32];
    const int t    = threadIdx.x;
    const int lane = t & 63;
    const int wid  = t >> 6;
    const int wm   = (wid & 1) * 64;
    const int wn   = (wid >> 1) * 64;
    const int quad = lane >> 4;
    const int l16  = lane & 15;
    const int bz   = blockIdx.z;

    const long rowA0 = (long)blockIdx.y * 128;
    const long colB0 = (long)blockIdx.x * 128;
    const u16* Ab = A + (long)bz * sA + rowA0 * lda;
    const u16* Bb = B + (long)bz * sB + colB0 * ldb;

    // staging: 256 threads x 16B; chunk j covers 64 rows (4 lanes/row)
    const int r4  = t >> 2;        // 0..63
    const int cEl = (t & 3) * 8;   // element offset in k
    const u16* gA0 = Ab + (long)r4 * lda + cEl;
    const u16* gA1 = Ab + (long)(64 + r4) * lda + cEl;
    const u16* gB0 = Bb + (long)r4 * ldb + cEl;
    const u16* gB1 = Bb + (long)(64 + r4) * ldb + cEl;
    u16* lA0 = &lA[r4 * 32 + cEl];
    u16* lA1 = &lA[(64 + r4) * 32 + cEl];
    u16* lB0 = &lB[r4 * 32 + cEl];
    u16* lB1 = &lB[(64 + r4) * 32 + cEl];

    f32x4 acc[4][4];
    #pragma unroll
    for (int i = 0; i < 4; i++)
        #pragma unroll
        for (int j = 0; j < 4; j++) {
            f32x4 z = {0.f, 0.f, 0.f, 0.f};
            acc[i][j] = z;
        }

    const u16* fA = &lA[(wm + l16) * 32 + quad * 8];
    const u16* fB = &lB[(wn + l16) * 32 + quad * 8];

    for (int k0 = 0; k0 < K; k0 += 32) {
        __builtin_amdgcn_global_load_lds(GPTR(gA0 + k0), LPTR(lA0), 16, 0, 0);
        __builtin_amdgcn_global_load_lds(GPTR(gA1 + k0), LPTR(lA1), 16, 0, 0);
        __builtin_amdgcn_global_load_lds(GPTR(gB0 + k0), LPTR(lB0), 16, 0, 0);
        __builtin_amdgcn_global_load_lds(GPTR(gB1 + k0), LPTR(lB1), 16, 0, 0);
        __syncthreads();
        bf16x8 a[4], b[4];
        #pragma unroll
        for (int mi = 0; mi < 4; mi++) a[mi] = *(const bf16x8*)(fA + mi * 16 * 32);
        #pragma unroll
        for (int ni = 0; ni < 4; ni++) b[ni] = *(const bf16x8*)(fB + ni * 16 * 32);
        #pragma unroll
        for (int mi = 0; mi < 4; mi++)
            #pragma unroll
            for (int ni = 0; ni < 4; ni++)
                acc[mi][ni] = __builtin_amdgcn_mfma_f32_16x16x32_bf16(a[mi], b[ni], acc[mi][ni], 0, 0, 0);
        __syncthreads();
    }

    float* Cf = (float*)Cout + (long)bz * sC;
    u16*   Cu = (u16*)Cout + (long)bz * sC;
    const long rbase = rowA0 + wm;
    const long cbase = colB0 + wn;
    #pragma unroll
    for (int mi = 0; mi < 4; mi++) {
        #pragma unroll
        for (int ni = 0; ni < 4; ni++) {
            const int col = (int)(cbase + ni * 16 + l16);
            float bv = 0.0f;
            if constexpr (MODE >= 2) bv = bias[col];
            #pragma unroll
            for (int r = 0; r < 4; r++) {
                const long row = rbase + mi * 16 + quad * 4 + r;
                float v = acc[mi][ni][r];
                if constexpr (MODE == 1) v *= scale;
                v += bv;
                if constexpr (MODE == 3 || MODE == 4) v = gelu_f(v);
                if constexpr (MODE == 4) v += bf2f(addend[row * (long)ldc + col]);
                if constexpr (MODE == 5) Cf[row * (long)ldc + col] = v;
                else                     Cu[row * (long)ldc + col] = f2bf(v);
            }
        }
    }
}

__global__ __launch_bounds__(256)
void cvt_bf16(const float* __restrict__ in, u16* __restrict__ out, long n)
{
    long i = ((long)blockIdx.x * 256 + threadIdx.x) * 4;
    if (i < n) {
        float4 v = *(const float4*)(in + i);
        u16x4 o = { f2bf(v.x), f2bf(v.y), f2bf(v.z), f2bf(v.w) };
        *(u16x4*)(out + i) = o;
    }
}

__global__ __launch_bounds__(256)
void ln_kernel(const u16* __restrict__ in, u16* __restrict__ out,
               const float* __restrict__ g, const float* __restrict__ b)
{
    const int row = blockIdx.x;
    const int t = threadIdx.x;
    const u16* r = in + (long)row * 1024;
    float x[4];
    float s = 0.f, s2 = 0.f;
    #pragma unroll
    for (int j = 0; j < 4; j++) { x[j] = bf2f(r[t + 256 * j]); s += x[j]; s2 += x[j] * x[j]; }
    __shared__ float sm[8];
    const int lane = t & 63, wid = t >> 6;
    #pragma unroll
    for (int o = 32; o > 0; o >>= 1) { s += __shfl_down(s, o, 64); s2 += __shfl_down(s2, o, 64); }
    if (lane == 0) { sm[wid] = s; sm[4 + wid] = s2; }
    __syncthreads();
    s  = sm[0] + sm[1] + sm[2] + sm[3];
    s2 = sm[4] + sm[5] + sm[6] + sm[7];
    const float mean = s * (1.f / 1024.f);
    const float var  = s2 * (1.f / 1024.f) - mean * mean;
    const float rstd = rsqrtf(var + 1e-5f);
    u16* o = out + (long)row * 1024;
    #pragma unroll
    for (int j = 0; j < 4; j++) {
        int c = t + 256 * j;
        o[c] = f2bf((x[j] - mean) * rstd * g[c] + b[c]);
    }
}

__global__ __launch_bounds__(256)
void softmax_kernel(u16* __restrict__ io)
{
    const int row = blockIdx.x;
    const int t = threadIdx.x;
    u16* r = io + (long)row * 1024;
    float x[4];
    float m = -1e30f;
    #pragma unroll
    for (int j = 0; j < 4; j++) { x[j] = bf2f(r[t + 256 * j]); m = fmaxf(m, x[j]); }
    __shared__ float sm[8];
    const int lane = t & 63, wid = t >> 6;
    #pragma unroll
    for (int o = 32; o > 0; o >>= 1) m = fmaxf(m, __shfl_down(m, o, 64));
    if (lane == 0) sm[wid] = m;
    __syncthreads();
    m = fmaxf(fmaxf(sm[0], sm[1]), fmaxf(sm[2], sm[3]));
    float e[4];
    float s = 0.f;
    #pragma unroll
    for (int j = 0; j < 4; j++) { e[j] = expf(x[j] - m); s += e[j]; }
    #pragma unroll
    for (int o = 32; o > 0; o >>= 1) s += __shfl_down(s, o, 64);
    if (lane == 0) sm[4 + wid] = s;
    __syncthreads();
    s = sm[4] + sm[5] + sm[6] + sm[7];
    const float inv = 1.f / s;
    #pragma unroll
    for (int j = 0; j < 4; j++) r[t + 256 * j] = f2bf(e[j] * inv);
}

// vT[b][c][t] = qkv[b*S + t][2C + c]
__global__ void transpose_v(const u16* __restrict__ qkv, u16* __restrict__ vT)
{
    __shared__ u16 tile[32][33];
    const int b  = blockIdx.z;
    const int t0 = blockIdx.x * 32;   // S index
    const int c0 = blockIdx.y * 32;   // C index
    const int tx = threadIdx.x, ty = threadIdx.y;
    #pragma unroll
    for (int i = ty; i < 32; i += 8)
        tile[i][tx] = qkv[((long)(b * 2048 + t0 + i)) * 3072 + 2048 + c0 + tx];
    __syncthreads();
    #pragma unroll
    for (int i = ty; i < 32; i += 8)
        vT[((long)(b * 1024 + c0 + i)) * 2048 + t0 + tx] = tile[tx][i];
}

__global__ __launch_bounds__(256)
void add_pe(float* __restrict__ out)
{
    long i = (long)blockIdx.x * 256 + threadIdx.x;
    const int f = (int)(i & 1023);
    const int s = (int)((i >> 10) & 2047);
    // div = 1000^(-2f/1024) = exp(-f * 2*ln(1000)/1024)
    const float div = expf(-(float)f * 0.013491709529261986f);
    const float arg = (float)s * div;
    const float pe = (s & 1) ? cosf(arg) : sinf(arg);
    out[i] += pe;
}

extern "C" void kernel_launch(void* const* d_in, const int* in_sizes, int n_in,
                              void* d_out, int out_size, void* d_ws, size_t ws_size,
                              hipStream_t stream)
{
    const float* x        = (const float*)d_in[0];
    const float* fc_in_w  = (const float*)d_in[1];
    const float* fc_in_b  = (const float*)d_in[2];
    const float* ln_g     = (const float*)d_in[3];
    const float* ln_b     = (const float*)d_in[4];
    const float* qkv_w    = (const float*)d_in[5];
    const float* qkv_b    = (const float*)d_in[6];
    const float* proj_w   = (const float*)d_in[7];
    const float* proj_b   = (const float*)d_in[8];
    const float* fc_out_w = (const float*)d_in[9];
    const float* fc_out_b = (const float*)d_in[10];

    char* w = (char*)d_ws;
    size_t off = 0;
    auto carve = [&](size_t bytes) -> void* {
        void* p = w + off;
        off += (bytes + 255) & ~(size_t)255;
        return p;
    };
    // B=4,S=2048,C=1024 -> M=8192 rows
    u16* xb   = (u16*)carve(16777216);  // x bf16; reused as hY after fc_in
    u16* hY   = xb;
    u16* wfci = (u16*)carve(2097152);   // fc_in_w bf16
    u16* wqkv = (u16*)carve(25165824);  // qkv_w bf16 (4 layers)
    u16* wprj = (u16*)carve(8388608);   // proj_w bf16
    u16* wfco = (u16*)carve(2097152);   // fc_out_w bf16
    u16* t0   = (u16*)carve(50331648);  // qkv activations (8192x3072); att aliases first 16MB
    u16* att  = t0;
    u16* hX   = (u16*)carve(16777216);
    u16* pred = (u16*)carve(16777216);
    u16* vT   = (u16*)carve(16777216);  // (B, C, S)
    u16* sc   = (u16*)carve(33554432);  // scores (B, S, S)

    // fp32 -> bf16 conversions (counts are multiples of 1024)
    cvt_bf16<<<dim3(8192),  dim3(256), 0, stream>>>(x,        xb,   8388608);
    cvt_bf16<<<dim3(1024),  dim3(256), 0, stream>>>(fc_in_w,  wfci, 1048576);
    cvt_bf16<<<dim3(12288), dim3(256), 0, stream>>>(qkv_w,    wqkv, 12582912);
    cvt_bf16<<<dim3(4096),  dim3(256), 0, stream>>>(proj_w,   wprj, 4194304);
    cvt_bf16<<<dim3(1024),  dim3(256), 0, stream>>>(fc_out_w, wfco, 1048576);

    // fc_in: t0 = x @ fc_in_w^T + b   (8192x1024, K=1024)
    gemm_bt<2><<<dim3(8, 64, 1), 256, 0, stream>>>(xb, 1024, 0, wfci, 1024, 0,
                                                   t0, 1024, 0, fc_in_b, nullptr, 1024, 1.0f);
    // layernorm -> hX
    ln_kernel<<<8192, 256, 0, stream>>>(t0, hX, ln_g, ln_b);

    const u16* hin[4] = { hX, pred, hX, hY };
    u16* hout[4]      = { pred, hX, hY, hX };

    for (int i = 0; i < 4; i++) {
        // qkv = gelu(h @ qkv_w[i]^T + qkv_b[i])  (8192x3072, K=1024)
        gemm_bt<3><<<dim3(24, 64, 1), 256, 0, stream>>>(hin[i], 1024, 0,
            wqkv + (long)i * 3145728, 1024, 0, t0, 3072, 0,
            qkv_b + (long)i * 3072, nullptr, 1024, 1.0f);
        // vT[b][c][t] = v[b][t][c]
        transpose_v<<<dim3(64, 32, 4), dim3(32, 8), 0, stream>>>(t0, vT);
        // scores = q @ k^T * (1/C)   per batch (2048x2048, K=1024)
        gemm_bt<1><<<dim3(16, 16, 4), 256, 0, stream>>>(t0, 3072, 6291456,
            t0 + 1024, 3072, 6291456, sc, 2048, 4194304,
            nullptr, nullptr, 1024, 1.0f / 1024.0f);
        // att = scores @ v   per batch (2048x1024, K=2048); att aliases t0 (qkv dead now)
        gemm_bt<0><<<dim3(8, 16, 4), 256, 0, stream>>>(sc, 2048, 4194304,
            vT, 2048, 2097152, att, 1024, 2097152,
            nullptr, nullptr, 2048, 1.0f);
        // softmax over C, in place
        softmax_kernel<<<8192, 256, 0, stream>>>(att);
        // h = gelu(att @ proj_w[i]^T + proj_b[i]) [+ pred for i>0]
        if (i == 0)
            gemm_bt<3><<<dim3(8, 64, 1), 256, 0, stream>>>(att, 1024, 0,
                wprj, 1024, 0, hout[0], 1024, 0, proj_b, nullptr, 1024, 1.0f);
        else
            gemm_bt<4><<<dim3(8, 64, 1), 256, 0, stream>>>(att, 1024, 0,
                wprj + (long)i * 1048576, 1024, 0, hout[i], 1024, 0,
                proj_b + (long)i * 1024, pred, 1024, 1.0f);
    }

    // out = hX @ fc_out_w^T + b  (fp32 out)
    gemm_bt<5><<<dim3(8, 64, 1), 256, 0, stream>>>(hX, 1024, 0, wfco, 1024, 0,
                                                   d_out, 1024, 0, fc_out_b, nullptr, 1024, 1.0f);
    // + positional encoding
    add_pe<<<32768, 256, 0, stream>>>((float*)d_out);
}

// Round 2
// 1232.988 us; speedup vs baseline: 1.1113x; 1.1113x over previous
//
#include <hip/hip_runtime.h>
#include <math.h>

typedef unsigned short u16;
typedef __bf16 bf16x8 __attribute__((ext_vector_type(8)));
typedef float f32x4  __attribute__((ext_vector_type(4)));
typedef float f32x16 __attribute__((ext_vector_type(16)));
typedef u16   u16x4  __attribute__((ext_vector_type(4)));

#define GPTR(p) ((__attribute__((address_space(1))) void*)(p))
#define LPTR(p) ((__attribute__((address_space(3))) void*)(p))

__device__ __forceinline__ float bf2f(u16 h) { return __uint_as_float(((unsigned)h) << 16); }
__device__ __forceinline__ u16 f2bf(float f) {
    unsigned u = __float_as_uint(f);
    return (u16)((u + 0x7fffu + ((u >> 16) & 1u)) >> 16);
}
// tanh-form gelu: max abs err vs erf-form ~1e-3, ~8 VALU ops (one v_exp)
__device__ __forceinline__ float gelu_f(float x) {
    float u = 0.7978845608f * x * (1.0f + 0.044715f * x * x);
    float e = __expf(2.0f * u);
    float t = 1.0f - 2.0f / (e + 1.0f);
    return 0.5f * x * (1.0f + t);
}

// ---------------------------------------------------------------------------
// GEMM: C = epilogue(A(MxK) @ B(NxK)^T), bf16 in, fp32 acc.
// 128x128 block tile, 4 waves of 64x64, BK=32, mfma_f32_32x32x16_bf16.
// LDS tile row-major 128x32 (64B rows); 16B chunks XOR-swizzled:
//   LDS slot (r, c_l) holds global chunk c_g = c_l ^ (r&3)   (self-inverse)
// so the 32-row fragment reads hit 8 bank-groups/phase (the b128 floor).
// global_load_lds stays legal: thread t's LDS dest is still base + t*16.
// MODE: 0=none, 1=scale, 2=+bias, 3=+bias,gelu, 4=+bias,gelu,+addend, 5=+bias fp32-out
// ---------------------------------------------------------------------------
template<int MODE>
__global__ __launch_bounds__(256, 4)
void gemm_bt(const u16* __restrict__ A, int lda, long sA,
             const u16* __restrict__ B, int ldb, long sB,
             void* __restrict__ Cout, int ldc, long sC,
             const float* __restrict__ bias,
             const u16* __restrict__ addend,
             int K, float scale)
{
    __shared__ u16 lA[128 * 32];
    __shared__ u16 lB[128 * 32];
    const int t    = threadIdx.x;
    const int lane = t & 63;
    const int wid  = t >> 6;
    const int wm   = (wid & 1) * 64;
    const int wn   = (wid >> 1) * 64;
    const int m32  = lane & 31;       // row-in-32 for A/B frags
    const int h    = lane >> 5;       // k-half selector
    const int sw   = lane & 3;        // swizzle key (= row&3 for frag rows)
    const int bz   = blockIdx.z;

    const long rowA0 = (long)blockIdx.y * 128;
    const long colB0 = (long)blockIdx.x * 128;
    const u16* Ab = A + (long)bz * sA + rowA0 * lda;
    const u16* Bb = B + (long)bz * sB + colB0 * ldb;

    // staging: 256 threads x 16B; thread t covers row r4=t>>2, LDS chunk t&3,
    // which holds global chunk (t&3)^(r4&3).
    const int r4  = t >> 2;
    const int cg0 = ((t & 3) ^ (r4 & 3)) * 8;   // element offset of global chunk
    const u16* gA0 = Ab + (long)r4 * lda + cg0;
    const u16* gA1 = Ab + (long)(64 + r4) * lda + cg0;
    const u16* gB0 = Bb + (long)r4 * ldb + cg0;
    const u16* gB1 = Bb + (long)(64 + r4) * ldb + cg0;
    u16* lA0 = &lA[t * 8];            // == (r4*32 + (t&3)*8)
    u16* lA1 = &lA[2048 + t * 8];
    u16* lB0 = &lB[t * 8];
    u16* lB1 = &lB[2048 + t * 8];

    f32x16 acc[2][2];
    #pragma unroll
    for (int i = 0; i < 2; i++)
        #pragma unroll
        for (int j = 0; j < 2; j++)
            #pragma unroll
            for (int r = 0; r < 16; r++) acc[i][j][r] = 0.f;

    for (int k0 = 0; k0 < K; k0 += 32) {
        __builtin_amdgcn_global_load_lds(GPTR(gA0 + k0), LPTR(lA0), 16, 0, 0);
        __builtin_amdgcn_global_load_lds(GPTR(gA1 + k0), LPTR(lA1), 16, 0, 0);
        __builtin_amdgcn_global_load_lds(GPTR(gB0 + k0), LPTR(lB0), 16, 0, 0);
        __builtin_amdgcn_global_load_lds(GPTR(gB1 + k0), LPTR(lB1), 16, 0, 0);
        __syncthreads();
        bf16x8 a[2][2], b[2][2];
        #pragma unroll
        for (int mi = 0; mi < 2; mi++)
            #pragma unroll
            for (int kh = 0; kh < 2; kh++)
                a[mi][kh] = *(const bf16x8*)&lA[(wm + mi * 32 + m32) * 32 + (((kh * 2 + h) ^ sw) * 8)];
        #pragma unroll
        for (int ni = 0; ni < 2; ni++)
            #pragma unroll
            for (int kh = 0; kh < 2; kh++)
                b[ni][kh] = *(const bf16x8*)&lB[(wn + ni * 32 + m32) * 32 + (((kh * 2 + h) ^ sw) * 8)];
        #pragma unroll
        for (int mi = 0; mi < 2; mi++)
            #pragma unroll
            for (int ni = 0; ni < 2; ni++)
                #pragma unroll
                for (int kh = 0; kh < 2; kh++)
                    acc[mi][ni] = __builtin_amdgcn_mfma_f32_32x32x16_bf16(a[mi][kh], b[ni][kh], acc[mi][ni], 0, 0, 0);
        __syncthreads();
    }

    float* Cf = (float*)Cout + (long)bz * sC;
    u16*   Cu = (u16*)Cout + (long)bz * sC;
    const long rbase = rowA0 + wm;
    const long cbase = colB0 + wn;
    // C/D layout (m74/m101): col = lane&31, row = (reg&3) + 8*(reg>>2) + 4*(lane>>5)
    #pragma unroll
    for (int mi = 0; mi < 2; mi++) {
        #pragma unroll
        for (int ni = 0; ni < 2; ni++) {
            const int col = (int)(cbase + ni * 32 + m32);
            float bv = 0.0f;
            if constexpr (MODE >= 2) bv = bias[col];
            #pragma unroll
            for (int r = 0; r < 16; r++) {
                const long row = rbase + mi * 32 + (r & 3) + 8 * (r >> 2) + 4 * h;
                float v = acc[mi][ni][r];
                if constexpr (MODE == 1) v *= scale;
                v += bv;
                if constexpr (MODE == 3 || MODE == 4) v = gelu_f(v);
                if constexpr (MODE == 4) v += bf2f(addend[row * (long)ldc + col]);
                if constexpr (MODE == 5) Cf[row * (long)ldc + col] = v;
                else                     Cu[row * (long)ldc + col] = f2bf(v);
            }
        }
    }
}

// one launch converting all five fp32->bf16 segments
__global__ __launch_bounds__(256)
void cvt_all(const float* __restrict__ s0, u16* __restrict__ d0, long n0,
             const float* __restrict__ s1, u16* __restrict__ d1, long n1,
             const float* __restrict__ s2, u16* __restrict__ d2, long n2,
             const float* __restrict__ s3, u16* __restrict__ d3, long n3,
             const float* __restrict__ s4, u16* __restrict__ d4, long n4)
{
    long i = ((long)blockIdx.x * 256 + threadIdx.x) * 4;
    const float* s; u16* d;
    if      (i < n0)                    { s = s0;  d = d0; }
    else if ((i -= n0) < n1)            { s = s1;  d = d1; }
    else if ((i -= n1) < n2)            { s = s2;  d = d2; }
    else if ((i -= n2) < n3)            { s = s3;  d = d3; }
    else if ((i -= n3) < n4)            { s = s4;  d = d4; }
    else return;
    float4 v = *(const float4*)(s + i);
    u16x4 o = { f2bf(v.x), f2bf(v.y), f2bf(v.z), f2bf(v.w) };
    *(u16x4*)(d + i) = o;
}

__global__ __launch_bounds__(256)
void ln_kernel(const u16* __restrict__ in, u16* __restrict__ out,
               const float* __restrict__ g, const float* __restrict__ b)
{
    const int row = blockIdx.x;
    const int t = threadIdx.x;
    const u16* r = in + (long)row * 1024;
    float x[4];
    float s = 0.f, s2 = 0.f;
    #pragma unroll
    for (int j = 0; j < 4; j++) { x[j] = bf2f(r[t + 256 * j]); s += x[j]; s2 += x[j] * x[j]; }
    __shared__ float sm[8];
    const int lane = t & 63, wid = t >> 6;
    #pragma unroll
    for (int o = 32; o > 0; o >>= 1) { s += __shfl_down(s, o, 64); s2 += __shfl_down(s2, o, 64); }
    if (lane == 0) { sm[wid] = s; sm[4 + wid] = s2; }
    __syncthreads();
    s  = sm[0] + sm[1] + sm[2] + sm[3];
    s2 = sm[4] + sm[5] + sm[6] + sm[7];
    const float mean = s * (1.f / 1024.f);
    const float var  = s2 * (1.f / 1024.f) - mean * mean;
    const float rstd = rsqrtf(var + 1e-5f);
    u16* o = out + (long)row * 1024;
    #pragma unroll
    for (int j = 0; j < 4; j++) {
        int c = t + 256 * j;
        o[c] = f2bf((x[j] - mean) * rstd * g[c] + b[c]);
    }
}

__global__ __launch_bounds__(256)
void softmax_kernel(u16* __restrict__ io)
{
    const int row = blockIdx.x;
    const int t = threadIdx.x;
    u16* r = io + (long)row * 1024;
    float x[4];
    float m = -1e30f;
    #pragma unroll
    for (int j = 0; j < 4; j++) { x[j] = bf2f(r[t + 256 * j]); m = fmaxf(m, x[j]); }
    __shared__ float sm[8];
    const int lane = t & 63, wid = t >> 6;
    #pragma unroll
    for (int o = 32; o > 0; o >>= 1) m = fmaxf(m, __shfl_down(m, o, 64));
    if (lane == 0) sm[wid] = m;
    __syncthreads();
    m = fmaxf(fmaxf(sm[0], sm[1]), fmaxf(sm[2], sm[3]));
    float e[4];
    float s = 0.f;
    #pragma unroll
    for (int j = 0; j < 4; j++) { e[j] = __expf(x[j] - m); s += e[j]; }
    #pragma unroll
    for (int o = 32; o > 0; o >>= 1) s += __shfl_down(s, o, 64);
    if (lane == 0) sm[4 + wid] = s;
    __syncthreads();
    s = sm[4] + sm[5] + sm[6] + sm[7];
    const float inv = 1.f / s;
    #pragma unroll
    for (int j = 0; j < 4; j++) r[t + 256 * j] = f2bf(e[j] * inv);
}

// vT[b][c][t] = qkv[b*S + t][2C + c]
__global__ void transpose_v(const u16* __restrict__ qkv, u16* __restrict__ vT)
{
    __shared__ u16 tile[32][33];
    const int b  = blockIdx.z;
    const int t0 = blockIdx.x * 32;   // S index
    const int c0 = blockIdx.y * 32;   // C index
    const int tx = threadIdx.x, ty = threadIdx.y;
    #pragma unroll
    for (int i = ty; i < 32; i += 8)
        tile[i][tx] = qkv[((long)(b * 2048 + t0 + i)) * 3072 + 2048 + c0 + tx];
    __syncthreads();
    #pragma unroll
    for (int i = ty; i < 32; i += 8)
        vT[((long)(b * 1024 + c0 + i)) * 2048 + t0 + tx] = tile[tx][i];
}

__global__ __launch_bounds__(256)
void add_pe(float* __restrict__ out)
{
    long i = (long)blockIdx.x * 256 + threadIdx.x;
    const int f = (int)(i & 1023);
    const int s = (int)((i >> 10) & 2047);
    const float div = __expf(-(float)f * 0.013491709529261986f);
    const float arg = (float)s * div;
    const float pe = (s & 1) ? cosf(arg) : sinf(arg);
    out[i] += pe;
}

extern "C" void kernel_launch(void* const* d_in, const int* in_sizes, int n_in,
                              void* d_out, int out_size, void* d_ws, size_t ws_size,
                              hipStream_t stream)
{
    const float* x        = (const float*)d_in[0];
    const float* fc_in_w  = (const float*)d_in[1];
    const float* fc_in_b  = (const float*)d_in[2];
    const float* ln_g     = (const float*)d_in[3];
    const float* ln_b     = (const float*)d_in[4];
    const float* qkv_w    = (const float*)d_in[5];
    const float* qkv_b    = (const float*)d_in[6];
    const float* proj_w   = (const float*)d_in[7];
    const float* proj_b   = (const float*)d_in[8];
    const float* fc_out_w = (const float*)d_in[9];
    const float* fc_out_b = (const float*)d_in[10];

    char* w = (char*)d_ws;
    size_t off = 0;
    auto carve = [&](size_t bytes) -> void* {
        void* p = w + off;
        off += (bytes + 255) & ~(size_t)255;
        return p;
    };
    u16* xb   = (u16*)carve(16777216);  // x bf16; reused as hY
    u16* hY   = xb;
    u16* wfci = (u16*)carve(2097152);
    u16* wqkv = (u16*)carve(25165824);
    u16* wprj = (u16*)carve(8388608);
    u16* wfco = (u16*)carve(2097152);
    u16* t0   = (u16*)carve(50331648);  // qkv acts (8192x3072); att aliases
    u16* att  = t0;
    u16* hX   = (u16*)carve(16777216);
    u16* pred = (u16*)carve(16777216);
    u16* vT   = (u16*)carve(16777216);  // (B, C, S)
    u16* sc   = (u16*)carve(33554432);  // scores (B, S, S)

    // fp32 -> bf16, one launch (27,262,976 elements / 4 per thread)
    cvt_all<<<dim3(26624), dim3(256), 0, stream>>>(
        x, xb, 8388608L, fc_in_w, wfci, 1048576L, qkv_w, wqkv, 12582912L,
        proj_w, wprj, 4194304L, fc_out_w, wfco, 1048576L);

    // fc_in: t0 = x @ fc_in_w^T + b   (8192x1024, K=1024)
    gemm_bt<2><<<dim3(8, 64, 1), 256, 0, stream>>>(xb, 1024, 0, wfci, 1024, 0,
                                                   t0, 1024, 0, fc_in_b, nullptr, 1024, 1.0f);
    ln_kernel<<<8192, 256, 0, stream>>>(t0, hX, ln_g, ln_b);

    const u16* hin[4] = { hX, pred, hX, hY };
    u16* hout[4]      = { pred, hX, hY, hX };

    for (int i = 0; i < 4; i++) {
        // qkv = gelu(h @ qkv_w[i]^T + qkv_b[i])  (8192x3072, K=1024)
        gemm_bt<3><<<dim3(24, 64, 1), 256, 0, stream>>>(hin[i], 1024, 0,
            wqkv + (long)i * 3145728, 1024, 0, t0, 3072, 0,
            qkv_b + (long)i * 3072, nullptr, 1024, 1.0f);
        transpose_v<<<dim3(64, 32, 4), dim3(32, 8), 0, stream>>>(t0, vT);
        // scores = q @ k^T * (1/C)   (per batch 2048x2048, K=1024)
        gemm_bt<1><<<dim3(16, 16, 4), 256, 0, stream>>>(t0, 3072, 6291456,
            t0 + 1024, 3072, 6291456, sc, 2048, 4194304,
            nullptr, nullptr, 1024, 1.0f / 1024.0f);
        // att = scores @ v   (per batch 2048x1024, K=2048)
        gemm_bt<0><<<dim3(8, 16, 4), 256, 0, stream>>>(sc, 2048, 4194304,
            vT, 2048, 2097152, att, 1024, 2097152,
            nullptr, nullptr, 2048, 1.0f);
        softmax_kernel<<<8192, 256, 0, stream>>>(att);
        // h = gelu(att @ proj_w[i]^T + proj_b[i]) [+ pred for i>0]
        if (i == 0)
            gemm_bt<3><<<dim3(8, 64, 1), 256, 0, stream>>>(att, 1024, 0,
                wprj, 1024, 0, hout[0], 1024, 0, proj_b, nullptr, 1024, 1.0f);
        else
            gemm_bt<4><<<dim3(8, 64, 1), 256, 0, stream>>>(att, 1024, 0,
                wprj + (long)i * 1048576, 1024, 0, hout[i], 1024, 0,
                proj_b + (long)i * 1024, pred, 1024, 1.0f);
    }

    gemm_bt<5><<<dim3(8, 64, 1), 256, 0, stream>>>(hX, 1024, 0, wfco, 1024, 0,
                                                   d_out, 1024, 0, fc_out_b, nullptr, 1024, 1.0f);
    add_pe<<<32768, 256, 0, stream>>>((float*)d_out);
}